// Round 1
// baseline (85.346 us; speedup 1.0000x reference)
//
#include <hip/hip_runtime.h>
#include <math.h>

#define DEG2RAD 0.017453292519943295f
#define RAD2DEG 57.29577951308232f
#define TINYV   1e-6f

__global__ __launch_bounds__(256) void fk_kernel(const float* __restrict__ theta,
                                                 const float* __restrict__ dh,
                                                 float* __restrict__ out,
                                                 int B) {
    int b = blockIdx.x * blockDim.x + threadIdx.x;
    if (b >= B) return;

    // ---- load this row's 6 joint angles (degrees), 8B-aligned vector loads ----
    const float* tp = theta + (size_t)b * 6;
    float2 t01 = *(const float2*)(tp + 0);
    float2 t23 = *(const float2*)(tp + 2);
    float2 t45 = *(const float2*)(tp + 4);
    float th[6] = {t01.x, t01.y, t23.x, t23.y, t45.x, t45.y};

    // ---- chain T = T0 * T1 * ... * T5, keeping only rows 0..2 (row 3 = e3) ----
    float T[3][4];
    #pragma unroll
    for (int i = 0; i < 6; ++i) {
        // dh reads are wave-uniform (constant index) -> scalar loads
        float a_  = dh[i*4 + 0];
        float al  = dh[i*4 + 1] * DEG2RAD;
        float d_  = dh[i*4 + 2];
        float off = dh[i*4 + 3];
        float thr = (off + th[i]) * DEG2RAD;
        float s, c, sa, ca;
        __sincosf(thr, &s, &c);
        __sincosf(al,  &sa, &ca);

        if (i == 0) {
            T[0][0] = c;      T[0][1] = -s;     T[0][2] = 0.f;  T[0][3] = a_;
            T[1][0] = s * ca; T[1][1] = c * ca; T[1][2] = -sa;  T[1][3] = -sa * d_;
            T[2][0] = s * sa; T[2][1] = c * sa; T[2][2] = ca;   T[2][3] = ca * d_;
        } else {
            float sca = s * ca, cca = c * ca, ssa = s * sa, csa = c * sa;
            float nsd = -sa * d_, cad = ca * d_;
            #pragma unroll
            for (int r = 0; r < 3; ++r) {
                float t0 = T[r][0], t1 = T[r][1], t2 = T[r][2], t3 = T[r][3];
                T[r][0] = t0 * c   + t1 * sca + t2 * ssa;
                T[r][1] = -t0 * s  + t1 * cca + t2 * csa;
                T[r][2] =           -t1 * sa  + t2 * ca;
                T[r][3] = t0 * a_  + t1 * nsd + t2 * cad + t3;
            }
        }
    }

    // ---- Euler (ZYX-ish per reference) extraction ----
    float T00 = T[0][0], T01 = T[0][1], T02 = T[0][2];
    float T10 = T[1][0], T11 = T[1][1], T12 = T[1][2];
    float T22 = T[2][2];

    bool cond = (fabsf(T12) <= TINYV) && (fabsf(T22) <= TINYV);

    float A1 = atan2f(T10, T11) * RAD2DEG;
    float B1 = atan2f(T02, T22) * RAD2DEG;
    float A2 = atan2f(-T01, T00) * RAD2DEG;
    float Ar = A2 * DEG2RAD;
    float sA, cA;
    __sincosf(Ar, &sA, &cA);
    float B2 = atan2f(T02, cA * T00 - sA * T01) * RAD2DEG;
    float C2 = atan2f(-T12, T22) * RAD2DEG;

    float A  = cond ? A1 : A2;
    float Bd = cond ? B1 : B2;
    float C  = cond ? 0.f : C2;

    // ---- store [x, y, z, A, B, C] ----
    float* op = out + (size_t)b * 6;
    float2 o0 = {T[0][3], T[1][3]};
    float2 o1 = {T[2][3], A};
    float2 o2 = {Bd, C};
    *(float2*)(op + 0) = o0;
    *(float2*)(op + 2) = o1;
    *(float2*)(op + 4) = o2;
}

extern "C" void kernel_launch(void* const* d_in, const int* in_sizes, int n_in,
                              void* d_out, int out_size, void* d_ws, size_t ws_size,
                              hipStream_t stream) {
    const float* theta = (const float*)d_in[0];
    const float* dh    = (const float*)d_in[1];
    float* out = (float*)d_out;
    int B = in_sizes[0] / 6;  // 1048576
    int block = 256;
    int grid = (B + block - 1) / block;
    fk_kernel<<<grid, block, 0, stream>>>(theta, dh, out, B);
}

// Round 2
// 83.341 us; speedup vs baseline: 1.0241x; 1.0241x over previous
//
#include <hip/hip_runtime.h>
#include <math.h>

#define RAD2DEG 57.29577951308232f
#define INV360  (1.0f/360.0f)
#define TINYV   1e-6f

// sin/cos of (rev revolutions): hw v_sin/v_cos take revolutions; one v_fract
// range-reduction keeps us in the guaranteed-accurate domain.
__device__ __forceinline__ void sincos_rev(float rev, float* s, float* c) {
    float r = rev - floorf(rev);
    *s = __builtin_amdgcn_sinf(r);
    *c = __builtin_amdgcn_cosf(r);
}

// Octant-reduced atan2, 6-term minimax poly on [0,1]; max err ~1e-6 rad.
// ~15 VALU ops vs ~100+ for OCML atan2f.
__device__ __forceinline__ float fast_atan2f(float y, float x) {
    float ax = fabsf(x), ay = fabsf(y);
    float mx = fmaxf(ax, ay), mn = fminf(ax, ay);
    float q = mn * __builtin_amdgcn_rcpf(mx);
    q = (mx == 0.0f) ? 0.0f : q;          // atan2(0,0) = 0
    float s = q * q;
    float p =        -0.0117212f;
    p = fmaf(p, s,  0.05265332f);
    p = fmaf(p, s, -0.11643287f);
    p = fmaf(p, s,  0.19354346f);
    p = fmaf(p, s, -0.33262347f);
    p = fmaf(p, s,  0.99997726f);
    float r = p * q;
    r = (ay > ax)  ? (1.57079632679f - r) : r;
    r = (x < 0.0f) ? (3.14159265359f - r) : r;
    return copysignf(r, y);
}

// 2 rows per thread: 48B-aligned float4 loads/stores, alpha-trig amortized.
__global__ __launch_bounds__(256) void fk_kernel(const float* __restrict__ theta,
                                                 const float* __restrict__ dh,
                                                 float* __restrict__ out,
                                                 int Bpairs) {
    int p = blockIdx.x * blockDim.x + threadIdx.x;
    if (p >= Bpairs) return;

    const float4* tp = (const float4*)(theta + (size_t)p * 12);
    float4 f0 = tp[0];
    float4 f1 = tp[1];
    float4 f2 = tp[2];

    // wave-uniform DH-derived constants
    float a_[6], sa[6], ca[6], sad[6], cad[6], offr[6];
    #pragma unroll
    for (int i = 0; i < 6; ++i) {
        a_[i]   = dh[i*4+0];
        float d = dh[i*4+2];
        offr[i] = dh[i*4+3] * INV360;
        float sA, cA;
        sincos_rev(dh[i*4+1] * INV360, &sA, &cA);
        sa[i] = sA; ca[i] = cA;
        sad[i] = -sA * d;   // row1 translation term
        cad[i] =  cA * d;   // row2 translation term
    }

    float th[2][6] = {{f0.x, f0.y, f0.z, f0.w, f1.x, f1.y},
                      {f1.z, f1.w, f2.x, f2.y, f2.z, f2.w}};
    float res[2][6];

    #pragma unroll
    for (int rr = 0; rr < 2; ++rr) {
        float T00,T01,T02,T03, T10,T11,T12,T13, T20,T21,T22,T23;
        {
            float s, c;
            sincos_rev(fmaf(th[rr][0], INV360, offr[0]), &s, &c);
            T00 = c;         T01 = -s;         T02 = 0.f;     T03 = a_[0];
            T10 = s * ca[0]; T11 = c * ca[0];  T12 = -sa[0];  T13 = sad[0];
            T20 = s * sa[0]; T21 = c * sa[0];  T22 = ca[0];   T23 = cad[0];
        }
        #pragma unroll
        for (int i = 1; i < 6; ++i) {
            float s, c;
            sincos_rev(fmaf(th[rr][i], INV360, offr[i]), &s, &c);
            float sca = s * ca[i], cca = c * ca[i];
            float ssa = s * sa[i], csa = c * sa[i];
            float n0, n1, n2, n3;
            n0 =  T00*c + T01*sca + T02*ssa;
            n1 = -T00*s + T01*cca + T02*csa;
            n2 =          -T01*sa[i] + T02*ca[i];
            n3 =  T00*a_[i] + T01*sad[i] + T02*cad[i] + T03;
            T00=n0; T01=n1; T02=n2; T03=n3;
            n0 =  T10*c + T11*sca + T12*ssa;
            n1 = -T10*s + T11*cca + T12*csa;
            n2 =          -T11*sa[i] + T12*ca[i];
            n3 =  T10*a_[i] + T11*sad[i] + T12*cad[i] + T13;
            T10=n0; T11=n1; T12=n2; T13=n3;
            n0 =  T20*c + T21*sca + T22*ssa;
            n1 = -T20*s + T21*cca + T22*csa;
            n2 =          -T21*sa[i] + T22*ca[i];
            n3 =  T20*a_[i] + T21*sad[i] + T22*cad[i] + T23;
            T20=n0; T21=n1; T22=n2; T23=n3;
        }

        bool cond = (fabsf(T12) <= TINYV) && (fabsf(T22) <= TINYV);
        // B2: cos(A2)*T00 - sin(A2)*T01 == hypot(T00,T01) exactly -> no sincos
        float A  = fast_atan2f(-T01, T00) * RAD2DEG;
        float Bd = fast_atan2f(T02, __builtin_amdgcn_sqrtf(fmaf(T00,T00,T01*T01))) * RAD2DEG;
        float C  = fast_atan2f(-T12, T22) * RAD2DEG;
        if (__ballot(cond)) {   // essentially never taken; wave-uniform skip
            float A1 = fast_atan2f(T10, T11) * RAD2DEG;
            float B1 = fast_atan2f(T02, T22) * RAD2DEG;
            A  = cond ? A1  : A;
            Bd = cond ? B1  : Bd;
            C  = cond ? 0.f : C;
        }
        res[rr][0] = T03; res[rr][1] = T13; res[rr][2] = T23;
        res[rr][3] = A;   res[rr][4] = Bd;  res[rr][5] = C;
    }

    float4* op = (float4*)(out + (size_t)p * 12);
    op[0] = make_float4(res[0][0], res[0][1], res[0][2], res[0][3]);
    op[1] = make_float4(res[0][4], res[0][5], res[1][0], res[1][1]);
    op[2] = make_float4(res[1][2], res[1][3], res[1][4], res[1][5]);
}

extern "C" void kernel_launch(void* const* d_in, const int* in_sizes, int n_in,
                              void* d_out, int out_size, void* d_ws, size_t ws_size,
                              hipStream_t stream) {
    const float* theta = (const float*)d_in[0];
    const float* dh    = (const float*)d_in[1];
    float* out = (float*)d_out;
    int Bpairs = in_sizes[0] / 12;   // 524288 pairs of rows
    int block = 256;
    int grid = (Bpairs + block - 1) / block;
    fk_kernel<<<grid, block, 0, stream>>>(theta, dh, out, Bpairs);
}